// Round 12
// baseline (360.849 us; speedup 1.0000x reference)
//
#include <hip/hip_runtime.h>
#include <math.h>

// Problem constants: B=2, S=4096, D=768, H=12, HD=64
#define B_  2
#define S_  4096
#define D_  768
#define H_  12
#define HD_ 64

using bf16x8  = __attribute__((ext_vector_type(8))) __bf16;
using f32x4   = __attribute__((ext_vector_type(4))) float;
using ushort8 = __attribute__((ext_vector_type(8))) unsigned short;
using uintv2  = __attribute__((ext_vector_type(2))) unsigned;
using uintv4  = __attribute__((ext_vector_type(4))) unsigned;

// fp32 -> bf16 bits, round-to-nearest-even (epilogues)
__device__ __forceinline__ unsigned short f2b(float f) {
    union { float f; unsigned u; } x; x.f = f;
    unsigned r = x.u + 0x7fffu + ((x.u >> 16) & 1u);
    return (unsigned short)(r >> 16);
}
// two fp32 -> packed bf16 pair, round-half-up (hot paths; also the W-pack)
__device__ __forceinline__ unsigned pk2(float x, float y) {
    unsigned ux = __builtin_bit_cast(unsigned, x) + 0x8000u;
    unsigned uy = __builtin_bit_cast(unsigned, y) + 0x8000u;
    return (uy & 0xFFFF0000u) | (ux >> 16);
}
// packed bf16 pair via HW converter (RNE), lo in low half
__device__ __forceinline__ unsigned cvtpk(float lo, float hi) {
    unsigned r;
    asm("v_cvt_pk_bf16_f32 %0, %1, %2" : "=v"(r) : "v"(lo), "v"(hi));
    return r;
}
// lg-group transpose step: x carries values for target lg-groups {0,1},
// y for {2,3}; returns {word(from even lg), word(from odd lg)}.
__device__ __forceinline__ uintv2 xpose_pair(unsigned x, unsigned y) {
    uintv2 s = __builtin_amdgcn_permlane32_swap(x, y, false, false);
    return __builtin_amdgcn_permlane16_swap(s[0], s[1], false, false);
}

// ---------------------------------------------------------------------------
// Fused Q/K/V projection GEMM. W read as fp32 DIRECTLY (w_convert kernel
// eliminated); packed to bf16 with the same pk2 during staging -> LDS
// contents bit-identical to the previous two-kernel pipeline. Double-
// buffered, one barrier per K-iter, XCD-stripe decomposition, BN=256.
// z==0: Q (scaled into exp2 domain) -> Qp. z==1: K -> Kp.
// z==2: V -> transpose FUSED: writes Vt[b*H+h][d][s] directly.
// ---------------------------------------------------------------------------
__global__ __launch_bounds__(256, 2)
void qkv_gemm(const float* __restrict__ q, const float* __restrict__ k,
              const float* __restrict__ v,
              const float* __restrict__ Wq, const float* __restrict__ Wk,
              const float* __restrict__ Wv,
              const float* __restrict__ bq, const float* __restrict__ bk,
              const float* __restrict__ bv,
              unsigned short* __restrict__ Qp, unsigned short* __restrict__ Kp,
              unsigned short* __restrict__ Vt)
{
    constexpr int BM = 128, BN = 256, BK = 32, LDP = 40, NK = D_ / BK;
    // XCD-stripe decomposition: lin = 0..575
    const int lin = blockIdx.x;
    const int xcd = lin & 7, s = lin >> 3;      // 72 blocks per XCD
    const int z  = s / 24, rr = s % 24;         // z: 0..2
    const int bn = rr >> 3;                     // 0..2  (W-tile, shared by 8 bm)
    const int bm = xcd * 8 + (rr & 7);          // 0..63 (A-stripe local to XCD)

    const float* A    = (z == 0) ? q  : (z == 1) ? k  : v;
    const float* Wf   = (z == 0) ? Wq : (z == 1) ? Wk : Wv;
    const float* bias = (z == 0) ? bq : (z == 1) ? bk : bv;

    __shared__ __align__(16) unsigned short As[2][BM * LDP];  // 10 KB x2
    __shared__ __align__(16) unsigned short Bs[2][BN * LDP];  // 20 KB x2

    const int tid = threadIdx.x;
    const int w = tid >> 6, lane = tid & 63, lr = lane & 15, lg = lane >> 4;
    const int wm = (w >> 1) * 64, wn = (w & 1) * 128;

    // staging geometry: A: 4 float4 (rows arow+t*32); B: 4x(2 float4) fp32
    const int arow = tid >> 3, ac4 = (tid & 7) * 4;
    const int brow = tid >> 2, bc8 = (tid & 3) * 8;
    const float* Abase = A + (size_t)(bm * BM + arow) * D_ + ac4;
    const float* Wbase = Wf + (size_t)(bn * BN + brow) * D_ + bc8;

    float4 ap[4], bp0[4], bp1[4];

    // prologue: k0 = 0 into buffer 0
    for (int t = 0; t < 4; ++t) ap[t] = *(const float4*)(Abase + (size_t)t * 32 * D_);
    for (int t = 0; t < 4; ++t) {
        bp0[t] = *(const float4*)(Wbase + (size_t)t * 64 * D_);
        bp1[t] = *(const float4*)(Wbase + (size_t)t * 64 * D_ + 4);
    }
    for (int t = 0; t < 4; ++t)
        *(uint2*)&As[0][(arow + t * 32) * LDP + ac4] =
            make_uint2(pk2(ap[t].x, ap[t].y), pk2(ap[t].z, ap[t].w));
    for (int t = 0; t < 4; ++t)
        *(uint4*)&Bs[0][(brow + t * 64) * LDP + bc8] =
            make_uint4(pk2(bp0[t].x, bp0[t].y), pk2(bp0[t].z, bp0[t].w),
                       pk2(bp1[t].x, bp1[t].y), pk2(bp1[t].z, bp1[t].w));
    __syncthreads();

    f32x4 acc[4][8] = {};

    for (int it = 0; it < NK; ++it) {
        const int cur = it & 1;
        // issue next tile's global loads (clamped on last iter)
        const int k2 = ((it + 1 < NK) ? it + 1 : it) * BK;
        for (int t = 0; t < 4; ++t) ap[t] = *(const float4*)(Abase + k2 + (size_t)t * 32 * D_);
        for (int t = 0; t < 4; ++t) {
            bp0[t] = *(const float4*)(Wbase + k2 + (size_t)t * 64 * D_);
            bp1[t] = *(const float4*)(Wbase + k2 + (size_t)t * 64 * D_ + 4);
        }

        // compute current buffer
        bf16x8 af[4], bfr[8];
        for (int i = 0; i < 4; ++i) af[i]  = *(const bf16x8*)&As[cur][(wm + i * 16 + lr) * LDP + lg * 8];
        for (int j = 0; j < 8; ++j) bfr[j] = *(const bf16x8*)&Bs[cur][(wn + j * 16 + lr) * LDP + lg * 8];
        for (int i = 0; i < 4; ++i)
            for (int j = 0; j < 8; ++j)
                acc[i][j] = __builtin_amdgcn_mfma_f32_16x16x32_bf16(af[i], bfr[j], acc[i][j], 0, 0, 0);

        // pack/write next buffer; one barrier
        const int nxt = cur ^ 1;
        for (int t = 0; t < 4; ++t)
            *(uint2*)&As[nxt][(arow + t * 32) * LDP + ac4] =
                make_uint2(pk2(ap[t].x, ap[t].y), pk2(ap[t].z, ap[t].w));
        for (int t = 0; t < 4; ++t)
            *(uint4*)&Bs[nxt][(brow + t * 64) * LDP + bc8] =
                make_uint4(pk2(bp0[t].x, bp0[t].y), pk2(bp0[t].z, bp0[t].w),
                           pk2(bp1[t].x, bp1[t].y), pk2(bp1[t].z, bp1[t].w));
        __syncthreads();
    }

    if (z == 2) {
        // fused transpose epilogue: element (s_g, col) -> Vt[b*H+h][d][s_in],
        // 4 consecutive s per lane pack into one 8 B store.
        for (int j = 0; j < 8; ++j) {
            const int col = bn * BN + wn + j * 16 + lr;
            const int hh = col >> 6, dd = col & 63;
            const float bv_ = bias[col];
            for (int i = 0; i < 4; ++i) {
                const int s_g = bm * BM + wm + i * 16 + lg * 4;
                const int bb = s_g >> 12, s_in = s_g & 4095;
                unsigned short e0 = f2b(acc[i][j][0] + bv_);
                unsigned short e1 = f2b(acc[i][j][1] + bv_);
                unsigned short e2 = f2b(acc[i][j][2] + bv_);
                unsigned short e3 = f2b(acc[i][j][3] + bv_);
                *(uint2*)(Vt + ((size_t)((bb * H_ + hh) * HD_ + dd)) * S_ + s_in) =
                    make_uint2((unsigned)e0 | ((unsigned)e1 << 16),
                               (unsigned)e2 | ((unsigned)e3 << 16));
            }
        }
    } else {
        unsigned short* C = (z == 0) ? Qp : Kp;
        const float qscale = 0.18033688011112042f;  // 0.125 * log2(e)
        for (int i = 0; i < 4; ++i) {
            int row0 = bm * BM + wm + i * 16 + lg * 4;
            for (int j = 0; j < 8; ++j) {
                int col = bn * BN + wn + j * 16 + lr;
                float bv_ = bias[col];
                for (int r = 0; r < 4; ++r) {
                    float val = acc[i][j][r] + bv_;
                    if (z == 0) val *= qscale;
                    C[(size_t)(row0 + r) * D_ + col] = f2b(val);
                }
            }
        }
    }
}

// ---------------------------------------------------------------------------
// Output GEMM: out = feats(bf16) @ Wo(fp32, packed inline)^T + bo, fp32 out.
// BM=64 / BN=128, grid 768 = exactly 3 blocks/CU. Double-buffered + XCD-stripe.
// ---------------------------------------------------------------------------
__global__ __launch_bounds__(256)
void o_gemm(const unsigned short* __restrict__ Ai, const float* __restrict__ W,
            const float* __restrict__ bias, float* __restrict__ C)
{
    constexpr int BM = 64, BN = 128, BK = 32, LDP = 40, NK = D_ / BK;
    __shared__ __align__(16) unsigned short As[2][BM * LDP];   // 5 KB x2
    __shared__ __align__(16) unsigned short Bs[2][BN * LDP];   // 10 KB x2

    const int lin = blockIdx.x;                 // 0..767
    const int xcd = lin & 7, s = lin >> 3;      // 96 blocks per XCD
    const int bn = s >> 4;                      // 0..5
    const int bm = xcd * 16 + (s & 15);         // 0..127

    const int tid = threadIdx.x;
    const int w = tid >> 6, lane = tid & 63, lr = lane & 15, lg = lane >> 4;
    const int wm = (w >> 1) * 32, wn = (w & 1) * 64;

    const int arow = tid >> 2, ac8 = (tid & 3) * 8;   // rows 0..63
    const unsigned short* Abase = Ai + (size_t)(bm * BM + arow) * D_ + ac8;
    const float* Wbase = W + (size_t)(bn * BN + arow) * D_ + ac8;

    ushort8 apre; float4 bp0[2], bp1[2];
    apre = *(const ushort8*)(Abase);
    for (int t = 0; t < 2; ++t) {
        bp0[t] = *(const float4*)(Wbase + (size_t)t * 64 * D_);
        bp1[t] = *(const float4*)(Wbase + (size_t)t * 64 * D_ + 4);
    }
    *(ushort8*)&As[0][arow * LDP + ac8] = apre;
    for (int t = 0; t < 2; ++t)
        *(uint4*)&Bs[0][(arow + t * 64) * LDP + ac8] =
            make_uint4(pk2(bp0[t].x, bp0[t].y), pk2(bp0[t].z, bp0[t].w),
                       pk2(bp1[t].x, bp1[t].y), pk2(bp1[t].z, bp1[t].w));
    __syncthreads();

    f32x4 acc[2][4] = {};

    for (int it = 0; it < NK; ++it) {
        const int cur = it & 1;
        const int k2 = ((it + 1 < NK) ? it + 1 : it) * BK;
        apre = *(const ushort8*)(Abase + k2);
        for (int t = 0; t < 2; ++t) {
            bp0[t] = *(const float4*)(Wbase + k2 + (size_t)t * 64 * D_);
            bp1[t] = *(const float4*)(Wbase + k2 + (size_t)t * 64 * D_ + 4);
        }

        bf16x8 af[2], bfr[4];
        for (int i = 0; i < 2; ++i) af[i]  = *(const bf16x8*)&As[cur][(wm + i * 16 + lr) * LDP + lg * 8];
        for (int j = 0; j < 4; ++j) bfr[j] = *(const bf16x8*)&Bs[cur][(wn + j * 16 + lr) * LDP + lg * 8];
        for (int i = 0; i < 2; ++i)
            for (int j = 0; j < 4; ++j)
                acc[i][j] = __builtin_amdgcn_mfma_f32_16x16x32_bf16(af[i], bfr[j], acc[i][j], 0, 0, 0);

        const int nxt = cur ^ 1;
        *(ushort8*)&As[nxt][arow * LDP + ac8] = apre;
        for (int t = 0; t < 2; ++t)
            *(uint4*)&Bs[nxt][(arow + t * 64) * LDP + ac8] =
                make_uint4(pk2(bp0[t].x, bp0[t].y), pk2(bp0[t].z, bp0[t].w),
                           pk2(bp1[t].x, bp1[t].y), pk2(bp1[t].z, bp1[t].w));
        __syncthreads();
    }

    for (int i = 0; i < 2; ++i) {
        int row0 = bm * BM + wm + i * 16 + lg * 4;
        for (int j = 0; j < 4; ++j) {
            int col = bn * BN + wn + j * 16 + lr;
            float bv_ = bias[col];
            for (int r = 0; r < 4; ++r)
                C[(size_t)(row0 + r) * D_ + col] = acc[i][j][r] + bv_;
        }
    }
}

// ---------------------------------------------------------------------------
// Flash attention (causal), exp2 domain, fixed-reference softmax, operand-
// swapped (S^T = K@Q^T, O^T = V^T@P^T), MERGED q-tile pair, in-register P
// redistribution (cvt_pk + permlane), double-buffered K/V staging with one
// barrier per stage, balanced per-CU pair mapping. R10-exact form (measured
// 92 us three times). Refuted on this structure: setprio (R6, -33%),
// vf-hoist (R9, -33%), reg-prefetch bundle (R1), 2x2 wave decomposition
// (R11: LDS conflicts halved as designed but ~210 live regs > 170 cap at
// 3 blocks/CU -> spill traffic +57 MB, net -4%).
// ---------------------------------------------------------------------------
__global__ __launch_bounds__(256)
void attn_kernel(const unsigned short* __restrict__ Qp,
                 const unsigned short* __restrict__ Kp,
                 const unsigned short* __restrict__ Vt,
                 unsigned short* __restrict__ feats)
{
    __shared__ __align__(16) unsigned short Ks[2][64 * 72];    // [buf][key][d+pad]
    __shared__ __align__(16) unsigned short Vs[2][64 * 72];    // [buf][d][key+pad]

    const int tid = threadIdx.x;
    const int lin = blockIdx.x + gridDim.x * blockIdx.y;       // 0..767
    const int xcd = lin & 7, idx = lin >> 3;                   // 96 per XCD
    const int bhl = idx >> 5;                                  // bh within xcd
    const int i   = idx & 31;
    int p;                                                     // balanced pair map
    if (bhl == 0)      p = i;
    else if (bhl == 1) p = (i + 16) & 31;
    else               p = (i < 16) ? (31 - 2 * i) : (62 - 2 * i);
    const int bh  = xcd * 3 + bhl;
    const int b = bh / H_, h = bh % H_;
    const int w = tid >> 6, lane = tid & 63, lr = lane & 15, lg = lane >> 4;

    const int qtA = 63 - p, qtB = p;                           // qtA > qtB always

    bf16x8 ones;
    for (int j = 0; j < 8; ++j) ones[j] = (__bf16)1.0f;

    const size_t kbase = ((size_t)b * S_) * D_ + h * HD_;
    const size_t vbase = ((size_t)bh * HD_) * S_;

    // Q fragments for both tiles (B-operand: col=q=lr, k=d=lg*8+j)
    const size_t qbA = ((size_t)(b * S_ + qtA * 64 + w * 16 + lr)) * D_ + h * HD_;
    const size_t qbB = ((size_t)(b * S_ + qtB * 64 + w * 16 + lr)) * D_ + h * HD_;
    bf16x8 qfA0 = *(const bf16x8*)(Qp + qbA + lg * 8);
    bf16x8 qfA1 = *(const bf16x8*)(Qp + qbA + 32 + lg * 8);
    bf16x8 qfB0 = *(const bf16x8*)(Qp + qbB + lg * 8);
    bf16x8 qfB1 = *(const bf16x8*)(Qp + qbB + 32 + lg * 8);

    f32x4 oA[4] = {}, oB[4] = {};
    f32x4 lA = {0.f, 0.f, 0.f, 0.f}, lB = {0.f, 0.f, 0.f, 0.f};

    const int nst = qtA + 1;

    // --- staging geometry: this thread owns rows (srow, srow+32), chunk sc8 ---
    const int srow = tid >> 3, sc8 = (tid & 7) * 8;
    const unsigned short* kpt = Kp + kbase + (size_t)srow * D_ + sc8;
    const unsigned short* vpt = Vt + vbase + (size_t)srow * S_ + sc8;
    unsigned short* KsW0 = &Ks[0][srow * 72 + sc8];
    unsigned short* VsW0 = &Vs[0][srow * 72 + sc8];
    unsigned short* KsW1 = &Ks[1][srow * 72 + sc8];
    unsigned short* VsW1 = &Vs[1][srow * 72 + sc8];

    // prologue: stage 0 into buffer 0
    {
        ushort8 a0 = *(const ushort8*)(kpt);
        ushort8 a1 = *(const ushort8*)(kpt + (size_t)32 * D_);
        ushort8 a2 = *(const ushort8*)(vpt);
        ushort8 a3 = *(const ushort8*)(vpt + (size_t)32 * S_);
        *(ushort8*)KsW0            = a0;
        *(ushort8*)(KsW0 + 32*72)  = a1;
        *(ushort8*)VsW0            = a2;
        *(ushort8*)(VsW0 + 32*72)  = a3;
    }
    __syncthreads();

    for (int kb = 0; kb < nst; ++kb) {
        const bool bAct = (kb <= qtB);
        const int cur = kb & 1;
        const unsigned short* Kc = Ks[cur];
        const unsigned short* Vc = Vs[cur];

        // ---- issue next stage's global loads (clamped on last iter) ----
        const int kb2 = (kb + 1 < nst) ? kb + 1 : kb;
        const unsigned short* kp2 = kpt + (size_t)kb2 * 64 * D_;
        const unsigned short* vp2 = vpt + (size_t)kb2 * 64;
        ushort8 kr0 = *(const ushort8*)(kp2);
        ushort8 kr1 = *(const ushort8*)(kp2 + (size_t)32 * D_);
        ushort8 vr0 = *(const ushort8*)(vp2);
        ushort8 vr1 = *(const ushort8*)(vp2 + (size_t)32 * S_);

        // ---- K fragments: read ONCE, shared by both tiles ----
        bf16x8 kf[4][2];
        for (int n = 0; n < 4; ++n) {
            kf[n][0] = *(const bf16x8*)&Kc[(n * 16 + lr) * 72 + lg * 8];
            kf[n][1] = *(const bf16x8*)&Kc[(n * 16 + lr) * 72 + 32 + lg * 8];
        }

        bf16x8 pfA0, pfA1, pfB0, pfB1;

        // ---- tile A: S^T = K @ Q^T, exp2, in-register P redistribution ----
        {
            f32x4 st[4];
            for (int n = 0; n < 4; ++n) {
                f32x4 s = {0.f, 0.f, 0.f, 0.f};
                s = __builtin_amdgcn_mfma_f32_16x16x32_bf16(kf[n][0], qfA0, s, 0, 0, 0);
                s = __builtin_amdgcn_mfma_f32_16x16x32_bf16(kf[n][1], qfA1, s, 0, 0, 0);
                st[n] = s;
            }
            if (kb == qtA) {
                for (int n = 0; n < 4; ++n)
                    for (int r = 0; r < 4; ++r)
                        if (n * 16 + lg * 4 + r > w * 16 + lr) st[n][r] = -INFINITY;
            }
            unsigned a_[4][2];
            for (int n = 0; n < 4; ++n) {
                float e0 = __builtin_amdgcn_exp2f(st[n][0]);
                float e1 = __builtin_amdgcn_exp2f(st[n][1]);
                float e2 = __builtin_amdgcn_exp2f(st[n][2]);
                float e3 = __builtin_amdgcn_exp2f(st[n][3]);
                a_[n][0] = cvtpk(e0, e1);
                a_[n][1] = cvtpk(e2, e3);
            }
            uintv2 p00 = xpose_pair(a_[0][0], a_[1][0]);   // pf0 words 0,2
            uintv2 p01 = xpose_pair(a_[0][1], a_[1][1]);   // pf0 words 1,3
            uintv2 p10 = xpose_pair(a_[2][0], a_[3][0]);   // pf1 words 0,2
            uintv2 p11 = xpose_pair(a_[2][1], a_[3][1]);   // pf1 words 1,3
            uintv4 w0 = {p00[0], p01[0], p00[1], p01[1]};
            uintv4 w1 = {p10[0], p11[0], p10[1], p11[1]};
            pfA0 = __builtin_bit_cast(bf16x8, w0);
            pfA1 = __builtin_bit_cast(bf16x8, w1);
        }
        // ---- tile B (same kf) ----
        if (bAct) {
            f32x4 st[4];
            for (int n = 0; n < 4; ++n) {
                f32x4 s = {0.f, 0.f, 0.f, 0.f};
                s = __builtin_amdgcn_mfma_f32_16x16x32_bf16(kf[n][0], qfB0, s, 0, 0, 0);
                s = __builtin_amdgcn_mfma_f32_16x16x32_bf16(kf[n][1], qfB1, s, 0, 0, 0);
                st[n] = s;
            }
            if (kb == qtB) {
                for (int n = 0; n < 4; ++n)
                    for (int r = 0; r < 4; ++r)
                        if (n * 16 + lg * 4 + r > w * 16 + lr) st[n][r] = -INFINITY;
            }
            unsigned a_[4][2];
            for (int n = 0; n < 4; ++n) {
                float e0 = __builtin_amdgcn_exp2f(st[n][0]);
                float e1 = __builtin_amdgcn_exp2f(st[n][1]);
                float e2 = __builtin_amdgcn_exp2f(st[n][2]);
                float e3 = __builtin_amdgcn_exp2f(st[n][3]);
                a_[n][0] = cvtpk(e0, e1);
                a_[n][1] = cvtpk(e2, e3);
            }
            uintv2 p00 = xpose_pair(a_[0][0], a_[1][0]);
            uintv2 p01 = xpose_pair(a_[0][1], a_[1][1]);
            uintv2 p10 = xpose_pair(a_[2][0], a_[3][0]);
            uintv2 p11 = xpose_pair(a_[2][1], a_[3][1]);
            uintv4 w0 = {p00[0], p01[0], p00[1], p01[1]};
            uintv4 w1 = {p10[0], p11[0], p10[1], p11[1]};
            pfB0 = __builtin_bit_cast(bf16x8, w0);
            pfB1 = __builtin_bit_cast(bf16x8, w1);
        }

        // ---- V fragments: read ONCE, shared by both tiles ----
        bf16x8 vf[4][2];
        for (int n = 0; n < 4; ++n) {
            vf[n][0] = *(const bf16x8*)&Vc[(n * 16 + lr) * 72 + lg * 8];
            vf[n][1] = *(const bf16x8*)&Vc[(n * 16 + lr) * 72 + 32 + lg * 8];
        }
        {
            for (int n = 0; n < 4; ++n) {
                oA[n] = __builtin_amdgcn_mfma_f32_16x16x32_bf16(vf[n][0], pfA0, oA[n], 0, 0, 0);
                oA[n] = __builtin_amdgcn_mfma_f32_16x16x32_bf16(vf[n][1], pfA1, oA[n], 0, 0, 0);
            }
            lA = __builtin_amdgcn_mfma_f32_16x16x32_bf16(ones, pfA0, lA, 0, 0, 0);
            lA = __builtin_amdgcn_mfma_f32_16x16x32_bf16(ones, pfA1, lA, 0, 0, 0);
        }
        if (bAct) {
            for (int n = 0; n < 4; ++n) {
                oB[n] = __builtin_amdgcn_mfma_f32_16x16x32_bf16(vf[n][0], pfB0, oB[n], 0, 0, 0);
                oB[n] = __builtin_amdgcn_mfma_f32_16x16x32_bf16(vf[n][1], pfB1, oB[n], 0, 0, 0);
            }
            lB = __builtin_amdgcn_mfma_f32_16x16x32_bf16(ones, pfB0, lB, 0, 0, 0);
            lB = __builtin_amdgcn_mfma_f32_16x16x32_bf16(ones, pfB1, lB, 0, 0, 0);
        }

        // ---- write next stage into the other buffer; one barrier ----
        if (cur == 0) {
            *(ushort8*)KsW1            = kr0;
            *(ushort8*)(KsW1 + 32*72)  = kr1;
            *(ushort8*)VsW1            = vr0;
            *(ushort8*)(VsW1 + 32*72)  = vr1;
        } else {
            *(ushort8*)KsW0            = kr0;
            *(ushort8*)(KsW0 + 32*72)  = kr1;
            *(ushort8*)VsW0            = vr0;
            *(ushort8*)(VsW0 + 32*72)  = vr1;
        }
        __syncthreads();
    }

    // ---- epilogues: lane holds O^T[d = n*16+lg*4..+3][q = lr] ----
    {
        const float inv = 1.0f / lA[0];
        const size_t obase = ((size_t)(b * S_ + qtA * 64 + w * 16 + lr)) * D_ + h * HD_;
        for (int n = 0; n < 4; ++n) {
            unsigned short e0 = f2b(oA[n][0] * inv), e1 = f2b(oA[n][1] * inv);
            unsigned short e2 = f2b(oA[n][2] * inv), e3 = f2b(oA[n][3] * inv);
            *(uint2*)(feats + obase + n * 16 + lg * 4) =
                make_uint2((unsigned)e0 | ((unsigned)e1 << 16),
                           (unsigned)e2 | ((unsigned)e3 << 16));
        }
    }
    {
        const float inv = 1.0f / lB[0];
        const size_t obase = ((size_t)(b * S_ + qtB * 64 + w * 16 + lr)) * D_ + h * HD_;
        for (int n = 0; n < 4; ++n) {
            unsigned short e0 = f2b(oB[n][0] * inv), e1 = f2b(oB[n][1] * inv);
            unsigned short e2 = f2b(oB[n][2] * inv), e3 = f2b(oB[n][3] * inv);
            *(uint2*)(feats + obase + n * 16 + lg * 4) =
                make_uint2((unsigned)e0 | ((unsigned)e1 << 16),
                           (unsigned)e2 | ((unsigned)e3 << 16));
        }
    }
}

// ---------------------------------------------------------------------------
extern "C" void kernel_launch(void* const* d_in, const int* in_sizes, int n_in,
                              void* d_out, int out_size, void* d_ws, size_t ws_size,
                              hipStream_t stream) {
    const float* q  = (const float*)d_in[0];
    const float* k  = (const float*)d_in[1];
    const float* v  = (const float*)d_in[2];
    // d_in[3] = mask (causal, analytic; not read)
    const float* Wq = (const float*)d_in[4];
    const float* bq = (const float*)d_in[5];
    const float* Wk = (const float*)d_in[6];
    const float* bk = (const float*)d_in[7];
    const float* Wv = (const float*)d_in[8];
    const float* bv = (const float*)d_in[9];
    const float* Wo = (const float*)d_in[10];
    const float* bo = (const float*)d_in[11];
    float* out = (float*)d_out;

    const size_t npro = (size_t)B_ * S_ * D_;   // 6,291,456
    unsigned short* Qp    = (unsigned short*)d_ws;
    unsigned short* Kp    = Qp + npro;
    unsigned short* feats = Kp + npro;          // attn output (bf16)
    unsigned short* Vt    = feats + npro;       // [b*H+h][d][s]

    dim3 blk(256);
    qkv_gemm<<<dim3(576), blk, 0, stream>>>(q, k, v, Wq, Wk, Wv, bq, bk, bv,
                                            Qp, Kp, Vt);
    attn_kernel<<<dim3(32, B_ * H_), blk, 0, stream>>>(Qp, Kp, Vt, feats);
    o_gemm<<<dim3(768), blk, 0, stream>>>(feats, Wo, bo, out);
}

// Round 13
// 321.829 us; speedup vs baseline: 1.1212x; 1.1212x over previous
//
#include <hip/hip_runtime.h>
#include <math.h>

// Problem constants: B=2, S=4096, D=768, H=12, HD=64
#define B_  2
#define S_  4096
#define D_  768
#define H_  12
#define HD_ 64

using bf16x8  = __attribute__((ext_vector_type(8))) __bf16;
using f32x4   = __attribute__((ext_vector_type(4))) float;
using ushort8 = __attribute__((ext_vector_type(8))) unsigned short;
using uintv2  = __attribute__((ext_vector_type(2))) unsigned;
using uintv4  = __attribute__((ext_vector_type(4))) unsigned;

// fp32 -> bf16 bits, round-to-nearest-even (epilogues)
__device__ __forceinline__ unsigned short f2b(float f) {
    union { float f; unsigned u; } x; x.f = f;
    unsigned r = x.u + 0x7fffu + ((x.u >> 16) & 1u);
    return (unsigned short)(r >> 16);
}
// two fp32 -> packed bf16 pair, round-half-up (hot paths)
__device__ __forceinline__ unsigned pk2(float x, float y) {
    unsigned ux = __builtin_bit_cast(unsigned, x) + 0x8000u;
    unsigned uy = __builtin_bit_cast(unsigned, y) + 0x8000u;
    return (uy & 0xFFFF0000u) | (ux >> 16);
}
// packed bf16 pair via HW converter (RNE), lo in low half
__device__ __forceinline__ unsigned cvtpk(float lo, float hi) {
    unsigned r;
    asm("v_cvt_pk_bf16_f32 %0, %1, %2" : "=v"(r) : "v"(lo), "v"(hi));
    return r;
}
// lg-group transpose step: x carries values for target lg-groups {0,1},
// y for {2,3}; returns {word(from even lg), word(from odd lg)}.
__device__ __forceinline__ uintv2 xpose_pair(unsigned x, unsigned y) {
    uintv2 s = __builtin_amdgcn_permlane32_swap(x, y, false, false);
    return __builtin_amdgcn_permlane16_swap(s[0], s[1], false, false);
}

// ---------------------------------------------------------------------------
// Convert the 4 weight matrices (589824 fp32 each) to bf16 once.
// (R12 proved folding this into the GEMMs costs ~15x its 2.4 us: fp32 W
// doubles staged bytes and puts pk2 on the K-loop critical path.)
// ---------------------------------------------------------------------------
__global__ __launch_bounds__(256)
void w_convert(const float* __restrict__ Wq, const float* __restrict__ Wk,
               const float* __restrict__ Wv, const float* __restrict__ Wo,
               unsigned short* __restrict__ Wb)
{
    const int z = blockIdx.y;
    const float* src = (z == 0) ? Wq : (z == 1) ? Wk : (z == 2) ? Wv : Wo;
    unsigned short* dst = Wb + (size_t)z * (D_ * D_);
    int idx = blockIdx.x * 256 + threadIdx.x;
    const float4 a = *(const float4*)(src + (size_t)idx * 8);
    const float4 b = *(const float4*)(src + (size_t)idx * 8 + 4);
    uint4 o;
    o.x = pk2(a.x, a.y); o.y = pk2(a.z, a.w);
    o.z = pk2(b.x, b.y); o.w = pk2(b.z, b.w);
    *(uint4*)(dst + (size_t)idx * 8) = o;
}

// ---------------------------------------------------------------------------
// Fused Q/K/V projection GEMM (W pre-converted bf16; A fp32 packed inline).
// Double-buffered, one barrier per K-iter, XCD-stripe decomposition.
// z==0: Q (scaled into exp2 domain) -> Qp. z==1: K -> Kp.
// z==2: V -> transpose FUSED: writes Vt[b*H+h][d][s] directly.
// ---------------------------------------------------------------------------
__global__ __launch_bounds__(256)
void qkv_gemm(const float* __restrict__ q, const float* __restrict__ k,
              const float* __restrict__ v,
              const unsigned short* __restrict__ Wb,
              const float* __restrict__ bq, const float* __restrict__ bk,
              const float* __restrict__ bv,
              unsigned short* __restrict__ Qp, unsigned short* __restrict__ Kp,
              unsigned short* __restrict__ Vt)
{
    constexpr int BM = 128, BN = 128, BK = 32, LDP = 40, NK = D_ / BK;
    // XCD-stripe decomposition: lin = 0..1151
    const int lin = blockIdx.x;
    const int xcd = lin & 7, s = lin >> 3;      // 144 blocks per XCD
    const int z  = s / 48, rr = s % 48;         // z: 0..2
    const int bn = rr >> 3;                     // 0..5  (W-tile, shared by 8 bm)
    const int bm = xcd * 8 + (rr & 7);          // 0..63 (A-stripe local to XCD)

    const float* A    = (z == 0) ? q  : (z == 1) ? k  : v;
    const unsigned short* W = Wb + (size_t)z * (D_ * D_);
    const float* bias = (z == 0) ? bq : (z == 1) ? bk : bv;

    __shared__ __align__(16) unsigned short As[2][BM * LDP];  // 10 KB x2
    __shared__ __align__(16) unsigned short Bs[2][BN * LDP];  // 10 KB x2

    const int tid = threadIdx.x;
    const int w = tid >> 6, lane = tid & 63, lr = lane & 15, lg = lane >> 4;
    const int wm = (w >> 1) * 64, wn = (w & 1) * 64;

    // staging geometry: A: 4 float4 chunks (rows arow+t*32); B: 2 ushort8
    const int arow = tid >> 3, ac4 = (tid & 7) * 4;
    const int brow = tid >> 2, bc8 = (tid & 3) * 8;
    const float* Abase = A + (size_t)(bm * BM + arow) * D_ + ac4;
    const unsigned short* Wbase = W + (size_t)(bn * BN + brow) * D_ + bc8;

    float4 ap[4]; ushort8 bp[2];

    // prologue: k0 = 0 into buffer 0
    for (int t = 0; t < 4; ++t) ap[t] = *(const float4*)(Abase + (size_t)t * 32 * D_);
    for (int t = 0; t < 2; ++t) bp[t] = *(const ushort8*)(Wbase + (size_t)t * 64 * D_);
    for (int t = 0; t < 4; ++t)
        *(uint2*)&As[0][(arow + t * 32) * LDP + ac4] =
            make_uint2(pk2(ap[t].x, ap[t].y), pk2(ap[t].z, ap[t].w));
    for (int t = 0; t < 2; ++t)
        *(ushort8*)&Bs[0][(brow + t * 64) * LDP + bc8] = bp[t];
    __syncthreads();

    f32x4 acc[4][4] = {};

    for (int it = 0; it < NK; ++it) {
        const int cur = it & 1;
        // issue next tile's global loads (clamped on last iter)
        const int k2 = ((it + 1 < NK) ? it + 1 : it) * BK;
        for (int t = 0; t < 4; ++t) ap[t] = *(const float4*)(Abase + k2 + (size_t)t * 32 * D_);
        for (int t = 0; t < 2; ++t) bp[t] = *(const ushort8*)(Wbase + k2 + (size_t)t * 64 * D_);

        // compute current buffer
        bf16x8 af[4], bfr[4];
        for (int i = 0; i < 4; ++i) af[i]  = *(const bf16x8*)&As[cur][(wm + i * 16 + lr) * LDP + lg * 8];
        for (int j = 0; j < 4; ++j) bfr[j] = *(const bf16x8*)&Bs[cur][(wn + j * 16 + lr) * LDP + lg * 8];
        for (int i = 0; i < 4; ++i)
            for (int j = 0; j < 4; ++j)
                acc[i][j] = __builtin_amdgcn_mfma_f32_16x16x32_bf16(af[i], bfr[j], acc[i][j], 0, 0, 0);

        // pack/write next buffer; one barrier
        const int nxt = cur ^ 1;
        for (int t = 0; t < 4; ++t)
            *(uint2*)&As[nxt][(arow + t * 32) * LDP + ac4] =
                make_uint2(pk2(ap[t].x, ap[t].y), pk2(ap[t].z, ap[t].w));
        for (int t = 0; t < 2; ++t)
            *(ushort8*)&Bs[nxt][(brow + t * 64) * LDP + bc8] = bp[t];
        __syncthreads();
    }

    if (z == 2) {
        // fused transpose epilogue: element (s_g, col) -> Vt[b*H+h][d][s_in],
        // 4 consecutive s per lane pack into one 8 B store.
        for (int j = 0; j < 4; ++j) {
            const int col = bn * BN + wn + j * 16 + lr;
            const int hh = col >> 6, dd = col & 63;
            const float bv_ = bias[col];
            for (int i = 0; i < 4; ++i) {
                const int s_g = bm * BM + wm + i * 16 + lg * 4;
                const int bb = s_g >> 12, s_in = s_g & 4095;
                unsigned short e0 = f2b(acc[i][j][0] + bv_);
                unsigned short e1 = f2b(acc[i][j][1] + bv_);
                unsigned short e2 = f2b(acc[i][j][2] + bv_);
                unsigned short e3 = f2b(acc[i][j][3] + bv_);
                *(uint2*)(Vt + ((size_t)((bb * H_ + hh) * HD_ + dd)) * S_ + s_in) =
                    make_uint2((unsigned)e0 | ((unsigned)e1 << 16),
                               (unsigned)e2 | ((unsigned)e3 << 16));
            }
        }
    } else {
        unsigned short* C = (z == 0) ? Qp : Kp;
        const float qscale = 0.18033688011112042f;  // 0.125 * log2(e)
        for (int i = 0; i < 4; ++i) {
            int row0 = bm * BM + wm + i * 16 + lg * 4;
            for (int j = 0; j < 4; ++j) {
                int col = bn * BN + wn + j * 16 + lr;
                float bv_ = bias[col];
                for (int r = 0; r < 4; ++r) {
                    float val = acc[i][j][r] + bv_;
                    if (z == 0) val *= qscale;
                    C[(size_t)(row0 + r) * D_ + col] = f2b(val);
                }
            }
        }
    }
}

// ---------------------------------------------------------------------------
// Output GEMM: out = feats(bf16) @ Wo(bf16)^T + bo, fp32 out. 128x64 tiles.
// Double-buffered + XCD-stripe decomposition; grid 768 = 3 blocks/CU.
// ---------------------------------------------------------------------------
__global__ __launch_bounds__(256)
void o_gemm(const unsigned short* __restrict__ Ai, const unsigned short* __restrict__ W,
            const float* __restrict__ bias, float* __restrict__ C)
{
    constexpr int BM = 128, BN = 64, BK = 32, LDP = 40, NK = D_ / BK;
    __shared__ __align__(16) unsigned short As[2][BM * LDP];
    __shared__ __align__(16) unsigned short Bs[2][BN * LDP];

    const int lin = blockIdx.x;                 // 0..767
    const int xcd = lin & 7, s = lin >> 3;      // 96 blocks per XCD
    const int bn = s >> 3;                      // 0..11
    const int bm = xcd * 8 + (s & 7);           // 0..63

    const int tid = threadIdx.x;
    const int w = tid >> 6, lane = tid & 63, lr = lane & 15, lg = lane >> 4;
    const int wm = (w >> 1) * 64, wn = (w & 1) * 32;

    const int arow = tid >> 2, ac8 = (tid & 3) * 8;  // A: 2 chunks, rows arow+t*64
    const unsigned short* Abase = Ai + (size_t)(bm * BM + arow) * D_ + ac8;
    const unsigned short* Wbase = W + (size_t)(bn * BN + arow) * D_ + ac8;  // arow<64 covers B

    ushort8 apre[2], bpre;
    for (int t = 0; t < 2; ++t) apre[t] = *(const ushort8*)(Abase + (size_t)t * 64 * D_);
    bpre = *(const ushort8*)(Wbase);
    for (int t = 0; t < 2; ++t)
        *(ushort8*)&As[0][(arow + t * 64) * LDP + ac8] = apre[t];
    *(ushort8*)&Bs[0][arow * LDP + ac8] = bpre;
    __syncthreads();

    f32x4 acc[4][2] = {};

    for (int it = 0; it < NK; ++it) {
        const int cur = it & 1;
        const int k2 = ((it + 1 < NK) ? it + 1 : it) * BK;
        for (int t = 0; t < 2; ++t) apre[t] = *(const ushort8*)(Abase + k2 + (size_t)t * 64 * D_);
        bpre = *(const ushort8*)(Wbase + k2);

        bf16x8 af[4], bfr[2];
        for (int i = 0; i < 4; ++i) af[i]  = *(const bf16x8*)&As[cur][(wm + i * 16 + lr) * LDP + lg * 8];
        for (int j = 0; j < 2; ++j) bfr[j] = *(const bf16x8*)&Bs[cur][(wn + j * 16 + lr) * LDP + lg * 8];
        for (int i = 0; i < 4; ++i)
            for (int j = 0; j < 2; ++j)
                acc[i][j] = __builtin_amdgcn_mfma_f32_16x16x32_bf16(af[i], bfr[j], acc[i][j], 0, 0, 0);

        const int nxt = cur ^ 1;
        for (int t = 0; t < 2; ++t)
            *(ushort8*)&As[nxt][(arow + t * 64) * LDP + ac8] = apre[t];
        *(ushort8*)&Bs[nxt][arow * LDP + ac8] = bpre;
        __syncthreads();
    }

    for (int i = 0; i < 4; ++i) {
        int row0 = bm * BM + wm + i * 16 + lg * 4;
        for (int j = 0; j < 2; ++j) {
            int col = bn * BN + wn + j * 16 + lr;
            float bv_ = bias[col];
            for (int r = 0; r < 4; ++r)
                C[(size_t)(row0 + r) * D_ + col] = acc[i][j][r] + bv_;
        }
    }
}

// ---------------------------------------------------------------------------
// Flash attention (causal), exp2 domain, fixed-reference softmax, operand-
// swapped (S^T = K@Q^T, O^T = V^T@P^T), MERGED q-tile pair, in-register P
// redistribution (cvt_pk + permlane), double-buffered K/V staging with one
// barrier per stage, balanced per-CU pair mapping. Session-best verified form
// (90.7-92.3 us across four runs). Refuted on this structure: setprio (R6),
// vf-hoist (R9), reg-prefetch bundle (R1), 2x2 wave decomp (R11, VGPR spill).
// ---------------------------------------------------------------------------
__global__ __launch_bounds__(256)
void attn_kernel(const unsigned short* __restrict__ Qp,
                 const unsigned short* __restrict__ Kp,
                 const unsigned short* __restrict__ Vt,
                 unsigned short* __restrict__ feats)
{
    __shared__ __align__(16) unsigned short Ks[2][64 * 72];    // [buf][key][d+pad]
    __shared__ __align__(16) unsigned short Vs[2][64 * 72];    // [buf][d][key+pad]

    const int tid = threadIdx.x;
    const int lin = blockIdx.x + gridDim.x * blockIdx.y;       // 0..767
    const int xcd = lin & 7, idx = lin >> 3;                   // 96 per XCD
    const int bhl = idx >> 5;                                  // bh within xcd
    const int i   = idx & 31;
    int p;                                                     // balanced pair map
    if (bhl == 0)      p = i;
    else if (bhl == 1) p = (i + 16) & 31;
    else               p = (i < 16) ? (31 - 2 * i) : (62 - 2 * i);
    const int bh  = xcd * 3 + bhl;
    const int b = bh / H_, h = bh % H_;
    const int w = tid >> 6, lane = tid & 63, lr = lane & 15, lg = lane >> 4;

    const int qtA = 63 - p, qtB = p;                           // qtA > qtB always

    bf16x8 ones;
    for (int j = 0; j < 8; ++j) ones[j] = (__bf16)1.0f;

    const size_t kbase = ((size_t)b * S_) * D_ + h * HD_;
    const size_t vbase = ((size_t)bh * HD_) * S_;

    // Q fragments for both tiles (B-operand: col=q=lr, k=d=lg*8+j)
    const size_t qbA = ((size_t)(b * S_ + qtA * 64 + w * 16 + lr)) * D_ + h * HD_;
    const size_t qbB = ((size_t)(b * S_ + qtB * 64 + w * 16 + lr)) * D_ + h * HD_;
    bf16x8 qfA0 = *(const bf16x8*)(Qp + qbA + lg * 8);
    bf16x8 qfA1 = *(const bf16x8*)(Qp + qbA + 32 + lg * 8);
    bf16x8 qfB0 = *(const bf16x8*)(Qp + qbB + lg * 8);
    bf16x8 qfB1 = *(const bf16x8*)(Qp + qbB + 32 + lg * 8);

    f32x4 oA[4] = {}, oB[4] = {};
    f32x4 lA = {0.f, 0.f, 0.f, 0.f}, lB = {0.f, 0.f, 0.f, 0.f};

    const int nst = qtA + 1;

    // --- staging geometry: this thread owns rows (srow, srow+32), chunk sc8 ---
    const int srow = tid >> 3, sc8 = (tid & 7) * 8;
    const unsigned short* kpt = Kp + kbase + (size_t)srow * D_ + sc8;
    const unsigned short* vpt = Vt + vbase + (size_t)srow * S_ + sc8;
    unsigned short* KsW0 = &Ks[0][srow * 72 + sc8];
    unsigned short* VsW0 = &Vs[0][srow * 72 + sc8];
    unsigned short* KsW1 = &Ks[1][srow * 72 + sc8];
    unsigned short* VsW1 = &Vs[1][srow * 72 + sc8];

    // prologue: stage 0 into buffer 0
    {
        ushort8 a0 = *(const ushort8*)(kpt);
        ushort8 a1 = *(const ushort8*)(kpt + (size_t)32 * D_);
        ushort8 a2 = *(const ushort8*)(vpt);
        ushort8 a3 = *(const ushort8*)(vpt + (size_t)32 * S_);
        *(ushort8*)KsW0            = a0;
        *(ushort8*)(KsW0 + 32*72)  = a1;
        *(ushort8*)VsW0            = a2;
        *(ushort8*)(VsW0 + 32*72)  = a3;
    }
    __syncthreads();

    for (int kb = 0; kb < nst; ++kb) {
        const bool bAct = (kb <= qtB);
        const int cur = kb & 1;
        const unsigned short* Kc = Ks[cur];
        const unsigned short* Vc = Vs[cur];

        // ---- issue next stage's global loads (clamped on last iter) ----
        const int kb2 = (kb + 1 < nst) ? kb + 1 : kb;
        const unsigned short* kp2 = kpt + (size_t)kb2 * 64 * D_;
        const unsigned short* vp2 = vpt + (size_t)kb2 * 64;
        ushort8 kr0 = *(const ushort8*)(kp2);
        ushort8 kr1 = *(const ushort8*)(kp2 + (size_t)32 * D_);
        ushort8 vr0 = *(const ushort8*)(vp2);
        ushort8 vr1 = *(const ushort8*)(vp2 + (size_t)32 * S_);

        // ---- K fragments: read ONCE, shared by both tiles ----
        bf16x8 kf[4][2];
        for (int n = 0; n < 4; ++n) {
            kf[n][0] = *(const bf16x8*)&Kc[(n * 16 + lr) * 72 + lg * 8];
            kf[n][1] = *(const bf16x8*)&Kc[(n * 16 + lr) * 72 + 32 + lg * 8];
        }

        bf16x8 pfA0, pfA1, pfB0, pfB1;

        // ---- tile A: S^T = K @ Q^T, exp2, in-register P redistribution ----
        {
            f32x4 st[4];
            for (int n = 0; n < 4; ++n) {
                f32x4 s = {0.f, 0.f, 0.f, 0.f};
                s = __builtin_amdgcn_mfma_f32_16x16x32_bf16(kf[n][0], qfA0, s, 0, 0, 0);
                s = __builtin_amdgcn_mfma_f32_16x16x32_bf16(kf[n][1], qfA1, s, 0, 0, 0);
                st[n] = s;
            }
            if (kb == qtA) {
                for (int n = 0; n < 4; ++n)
                    for (int r = 0; r < 4; ++r)
                        if (n * 16 + lg * 4 + r > w * 16 + lr) st[n][r] = -INFINITY;
            }
            unsigned a_[4][2];
            for (int n = 0; n < 4; ++n) {
                float e0 = __builtin_amdgcn_exp2f(st[n][0]);
                float e1 = __builtin_amdgcn_exp2f(st[n][1]);
                float e2 = __builtin_amdgcn_exp2f(st[n][2]);
                float e3 = __builtin_amdgcn_exp2f(st[n][3]);
                a_[n][0] = cvtpk(e0, e1);
                a_[n][1] = cvtpk(e2, e3);
            }
            uintv2 p00 = xpose_pair(a_[0][0], a_[1][0]);   // pf0 words 0,2
            uintv2 p01 = xpose_pair(a_[0][1], a_[1][1]);   // pf0 words 1,3
            uintv2 p10 = xpose_pair(a_[2][0], a_[3][0]);   // pf1 words 0,2
            uintv2 p11 = xpose_pair(a_[2][1], a_[3][1]);   // pf1 words 1,3
            uintv4 w0 = {p00[0], p01[0], p00[1], p01[1]};
            uintv4 w1 = {p10[0], p11[0], p10[1], p11[1]};
            pfA0 = __builtin_bit_cast(bf16x8, w0);
            pfA1 = __builtin_bit_cast(bf16x8, w1);
        }
        // ---- tile B (same kf) ----
        if (bAct) {
            f32x4 st[4];
            for (int n = 0; n < 4; ++n) {
                f32x4 s = {0.f, 0.f, 0.f, 0.f};
                s = __builtin_amdgcn_mfma_f32_16x16x32_bf16(kf[n][0], qfB0, s, 0, 0, 0);
                s = __builtin_amdgcn_mfma_f32_16x16x32_bf16(kf[n][1], qfB1, s, 0, 0, 0);
                st[n] = s;
            }
            if (kb == qtB) {
                for (int n = 0; n < 4; ++n)
                    for (int r = 0; r < 4; ++r)
                        if (n * 16 + lg * 4 + r > w * 16 + lr) st[n][r] = -INFINITY;
            }
            unsigned a_[4][2];
            for (int n = 0; n < 4; ++n) {
                float e0 = __builtin_amdgcn_exp2f(st[n][0]);
                float e1 = __builtin_amdgcn_exp2f(st[n][1]);
                float e2 = __builtin_amdgcn_exp2f(st[n][2]);
                float e3 = __builtin_amdgcn_exp2f(st[n][3]);
                a_[n][0] = cvtpk(e0, e1);
                a_[n][1] = cvtpk(e2, e3);
            }
            uintv2 p00 = xpose_pair(a_[0][0], a_[1][0]);
            uintv2 p01 = xpose_pair(a_[0][1], a_[1][1]);
            uintv2 p10 = xpose_pair(a_[2][0], a_[3][0]);
            uintv2 p11 = xpose_pair(a_[2][1], a_[3][1]);
            uintv4 w0 = {p00[0], p01[0], p00[1], p01[1]};
            uintv4 w1 = {p10[0], p11[0], p10[1], p11[1]};
            pfB0 = __builtin_bit_cast(bf16x8, w0);
            pfB1 = __builtin_bit_cast(bf16x8, w1);
        }

        // ---- V fragments: read ONCE, shared by both tiles ----
        bf16x8 vf[4][2];
        for (int n = 0; n < 4; ++n) {
            vf[n][0] = *(const bf16x8*)&Vc[(n * 16 + lr) * 72 + lg * 8];
            vf[n][1] = *(const bf16x8*)&Vc[(n * 16 + lr) * 72 + 32 + lg * 8];
        }
        {
            for (int n = 0; n < 4; ++n) {
                oA[n] = __builtin_amdgcn_mfma_f32_16x16x32_bf16(vf[n][0], pfA0, oA[n], 0, 0, 0);
                oA[n] = __builtin_amdgcn_mfma_f32_16x16x32_bf16(vf[n][1], pfA1, oA[n], 0, 0, 0);
            }
            lA = __builtin_amdgcn_mfma_f32_16x16x32_bf16(ones, pfA0, lA, 0, 0, 0);
            lA = __builtin_amdgcn_mfma_f32_16x16x32_bf16(ones, pfA1, lA, 0, 0, 0);
        }
        if (bAct) {
            for (int n = 0; n < 4; ++n) {
                oB[n] = __builtin_amdgcn_mfma_f32_16x16x32_bf16(vf[n][0], pfB0, oB[n], 0, 0, 0);
                oB[n] = __builtin_amdgcn_mfma_f32_16x16x32_bf16(vf[n][1], pfB1, oB[n], 0, 0, 0);
            }
            lB = __builtin_amdgcn_mfma_f32_16x16x32_bf16(ones, pfB0, lB, 0, 0, 0);
            lB = __builtin_amdgcn_mfma_f32_16x16x32_bf16(ones, pfB1, lB, 0, 0, 0);
        }

        // ---- write next stage into the other buffer; one barrier ----
        if (cur == 0) {
            *(ushort8*)KsW1            = kr0;
            *(ushort8*)(KsW1 + 32*72)  = kr1;
            *(ushort8*)VsW1            = vr0;
            *(ushort8*)(VsW1 + 32*72)  = vr1;
        } else {
            *(ushort8*)KsW0            = kr0;
            *(ushort8*)(KsW0 + 32*72)  = kr1;
            *(ushort8*)VsW0            = vr0;
            *(ushort8*)(VsW0 + 32*72)  = vr1;
        }
        __syncthreads();
    }

    // ---- epilogues: lane holds O^T[d = n*16+lg*4..+3][q = lr] ----
    {
        const float inv = 1.0f / lA[0];
        const size_t obase = ((size_t)(b * S_ + qtA * 64 + w * 16 + lr)) * D_ + h * HD_;
        for (int n = 0; n < 4; ++n) {
            unsigned short e0 = f2b(oA[n][0] * inv), e1 = f2b(oA[n][1] * inv);
            unsigned short e2 = f2b(oA[n][2] * inv), e3 = f2b(oA[n][3] * inv);
            *(uint2*)(feats + obase + n * 16 + lg * 4) =
                make_uint2((unsigned)e0 | ((unsigned)e1 << 16),
                           (unsigned)e2 | ((unsigned)e3 << 16));
        }
    }
    {
        const float inv = 1.0f / lB[0];
        const size_t obase = ((size_t)(b * S_ + qtB * 64 + w * 16 + lr)) * D_ + h * HD_;
        for (int n = 0; n < 4; ++n) {
            unsigned short e0 = f2b(oB[n][0] * inv), e1 = f2b(oB[n][1] * inv);
            unsigned short e2 = f2b(oB[n][2] * inv), e3 = f2b(oB[n][3] * inv);
            *(uint2*)(feats + obase + n * 16 + lg * 4) =
                make_uint2((unsigned)e0 | ((unsigned)e1 << 16),
                           (unsigned)e2 | ((unsigned)e3 << 16));
        }
    }
}

// ---------------------------------------------------------------------------
extern "C" void kernel_launch(void* const* d_in, const int* in_sizes, int n_in,
                              void* d_out, int out_size, void* d_ws, size_t ws_size,
                              hipStream_t stream) {
    const float* q  = (const float*)d_in[0];
    const float* k  = (const float*)d_in[1];
    const float* v  = (const float*)d_in[2];
    // d_in[3] = mask (causal, analytic; not read)
    const float* Wq = (const float*)d_in[4];
    const float* bq = (const float*)d_in[5];
    const float* Wk = (const float*)d_in[6];
    const float* bk = (const float*)d_in[7];
    const float* Wv = (const float*)d_in[8];
    const float* bv = (const float*)d_in[9];
    const float* Wo = (const float*)d_in[10];
    const float* bo = (const float*)d_in[11];
    float* out = (float*)d_out;

    const size_t npro = (size_t)B_ * S_ * D_;   // 6,291,456
    const size_t nw   = (size_t)D_ * D_;        // 589,824
    unsigned short* Qp    = (unsigned short*)d_ws;
    unsigned short* Kp    = Qp + npro;
    unsigned short* feats = Kp + npro;          // attn output (bf16)
    unsigned short* Vt    = feats + npro;       // [b*H+h][d][s]
    unsigned short* Wb    = Vt + npro;          // 4 bf16 weight matrices

    dim3 blk(256);
    w_convert<<<dim3(288, 4), blk, 0, stream>>>(Wq, Wk, Wv, Wo, Wb);
    qkv_gemm<<<dim3(1152), blk, 0, stream>>>(q, k, v, Wb, bq, bk, bv,
                                             Qp, Kp, Vt);
    attn_kernel<<<dim3(32, B_ * H_), blk, 0, stream>>>(Qp, Kp, Vt, feats);
    o_gemm<<<dim3(768), blk, 0, stream>>>(feats, Wb + 3 * nw, bo, out);
}